// Round 1
// baseline (5628.488 us; speedup 1.0000x reference)
//
#include <hip/hip_runtime.h>
#include <math.h>

#define NN 100000
#define DD 128
#define HH 64
#define KK 8
#define LL 3
#define CC 16
#define EE 1600000

// ---------------- degree / norm precompute (layer-invariant) ----------------

__global__ __launch_bounds__(256) void deg_kernel(const int* __restrict__ col,
                                                  float* __restrict__ deg) {
  int i = blockIdx.x * 256 + threadIdx.x;  // EE % 256 == 0
  unsafeAtomicAdd(&deg[col[i]], 1.0f);
}

__global__ __launch_bounds__(256) void dn_kernel(float* __restrict__ dn) {
  int i = blockIdx.x * 256 + threadIdx.x;
  if (i < NN) {
    float d = dn[i];
    dn[i] = d > 0.0f ? 1.0f / sqrtf(d) : 0.0f;  // exact-rounded, matches np 1/sqrt
  }
}

__global__ __launch_bounds__(256) void val_kernel(const int* __restrict__ row,
                                                  const int* __restrict__ col,
                                                  const float* __restrict__ dn,
                                                  float* __restrict__ val) {
  int i = blockIdx.x * 256 + threadIdx.x;  // EE % 256 == 0
  val[i] = dn[col[i]] * dn[row[i]];
}

// ---------------- fc0: h = relu(x @ fc0_w + b), [N,128]@[128,64] ----------------

__global__ __launch_bounds__(256) void fc0_kernel(const float* __restrict__ x,
                                                  const float* __restrict__ w,
                                                  const float* __restrict__ b,
                                                  float* __restrict__ h) {
  int id = blockIdx.x * 256 + threadIdx.x;  // (NN*HH) % 256 == 0
  int n = id >> 6, o = id & 63;
  const float* xr = x + n * DD;
  float s0 = 0.f, s1 = 0.f, s2 = 0.f, s3 = 0.f;
#pragma unroll
  for (int f = 0; f < DD; f += 4) {
    s0 = fmaf(xr[f + 0], w[(f + 0) * HH + o], s0);
    s1 = fmaf(xr[f + 1], w[(f + 1) * HH + o], s1);
    s2 = fmaf(xr[f + 2], w[(f + 2) * HH + o], s2);
    s3 = fmaf(xr[f + 3], w[(f + 3) * HH + o], s3);
  }
  h[id] = fmaxf((s0 + s1) + (s2 + s3) + b[o], 0.0f);
}

// ---------------- env gate: e = pi * (pi > theta), h_env == 0 always ----------------

__global__ __launch_bounds__(256) void env_kernel(const float* __restrict__ h,
                                                  const float* __restrict__ env_w,
                                                  const float* __restrict__ env_b,
                                                  float* __restrict__ e_out) {
  int n = blockIdx.x * 256 + threadIdx.x;
  if (n >= NN) return;
  float logit[KK];
#pragma unroll
  for (int k = 0; k < KK; ++k) logit[k] = env_b[k];
  const float4* hp = reinterpret_cast<const float4*>(h + n * HH);
#pragma unroll
  for (int f4 = 0; f4 < HH / 4; ++f4) {
    float4 hv = hp[f4];
    float hj[4] = {hv.x, hv.y, hv.z, hv.w};
#pragma unroll
    for (int j = 0; j < 4; ++j) {
      int f = f4 * 4 + j;
#pragma unroll
      for (int k = 0; k < KK; ++k)
        logit[k] = fmaf(hj[j], env_w[f * KK + k], logit[k]);
    }
  }
  float m = logit[0];
#pragma unroll
  for (int k = 1; k < KK; ++k) m = fmaxf(m, logit[k]);
  float p[KK];
  float s = 0.f;
#pragma unroll
  for (int k = 0; k < KK; ++k) {
    p[k] = expf(logit[k] - m);
    s += p[k];
  }
#pragma unroll
  for (int k = 0; k < KK; ++k) {
    float pi = p[k] / s;
    // replicate python: float pi promoted to double, compared against 0.1 (double)
    e_out[n * KK + k] = ((double)pi > 0.1) ? pi : 0.0f;
  }
}

// ---------------- GCN scatter: agg[col] += val * h[row], 16 threads/edge ----------------

__global__ __launch_bounds__(256) void scatter_kernel(const int* __restrict__ row,
                                                      const int* __restrict__ col,
                                                      const float* __restrict__ val,
                                                      const float* __restrict__ h,
                                                      float* __restrict__ agg) {
  int id = blockIdx.x * 256 + threadIdx.x;  // EE*16 threads exactly
  int e = id >> 4, part = id & 15;
  int r = row[e], c = col[e];
  float v = val[e];
  float4 hv = *reinterpret_cast<const float4*>(h + r * HH + part * 4);
  float* a = agg + c * HH + part * 4;
  unsafeAtomicAdd(a + 0, hv.x * v);
  unsafeAtomicAdd(a + 1, hv.y * v);
  unsafeAtomicAdd(a + 2, hv.z * v);
  unsafeAtomicAdd(a + 3, hv.w * v);
}

// ---------------- gated K-head conv + residual relu (in-place on h) ----------------
// out[n,o] = relu(h[n,o] + sum_k e[n,k] * sum_f hi[n,f] * w[k,f,o]), hi = [agg | h]

__global__ __launch_bounds__(256) void conv_kernel(float* __restrict__ h,
                                                   const float* __restrict__ agg,
                                                   const float* __restrict__ eg,
                                                   const float* __restrict__ w,
                                                   int unused) {
  int id = blockIdx.x * 256 + threadIdx.x;  // (NN*HH) % 256 == 0
  int n = id >> 6, o = id & 63;
  int ln = threadIdx.x >> 6;  // node slot within block (0..3)
  __shared__ float hi_s[4][2 * HH];
  hi_s[ln][o] = agg[n * HH + o];
  hi_s[ln][HH + o] = h[n * HH + o];
  __syncthreads();
  float acc = 0.f;
  for (int k = 0; k < KK; ++k) {
    float ek = eg[n * KK + k];
    if (ek != 0.0f) {  // wave-uniform: all 64 lanes share n
      const float* wk = w + k * (2 * HH * HH) + o;
      float s0 = 0.f, s1 = 0.f, s2 = 0.f, s3 = 0.f;
#pragma unroll
      for (int f = 0; f < 2 * HH; f += 4) {
        s0 = fmaf(hi_s[ln][f + 0], wk[(f + 0) * HH], s0);
        s1 = fmaf(hi_s[ln][f + 1], wk[(f + 1) * HH], s1);
        s2 = fmaf(hi_s[ln][f + 2], wk[(f + 2) * HH], s2);
        s3 = fmaf(hi_s[ln][f + 3], wk[(f + 3) * HH], s3);
      }
      acc = fmaf(ek, (s0 + s1) + (s2 + s3), acc);
    }
  }
  h[n * HH + o] = fmaxf(hi_s[ln][HH + o] + acc, 0.0f);
}

// ---------------- fc1: out = h @ fc1_w + b, [N,64]@[64,16] ----------------

__global__ __launch_bounds__(256) void fc1_kernel(const float* __restrict__ h,
                                                  const float* __restrict__ w,
                                                  const float* __restrict__ b,
                                                  float* __restrict__ out) {
  int id = blockIdx.x * 256 + threadIdx.x;  // (NN*CC) % 256 == 0
  int n = id >> 4, c = id & 15;
  const float* hr = h + n * HH;
  float acc = b[c];
#pragma unroll
  for (int o = 0; o < HH; ++o) acc = fmaf(hr[o], w[o * CC + c], acc);
  out[id] = acc;
}

// ---------------- launch ----------------

extern "C" void kernel_launch(void* const* d_in, const int* in_sizes, int n_in,
                              void* d_out, int out_size, void* d_ws, size_t ws_size,
                              hipStream_t stream) {
  const float* x      = (const float*)d_in[0];
  const int*   ei     = (const int*)d_in[1];
  const float* fc0_w  = (const float*)d_in[2];
  const float* fc0_b  = (const float*)d_in[3];
  const float* fc1_w  = (const float*)d_in[4];
  const float* fc1_b  = (const float*)d_in[5];
  const float* env_w  = (const float*)d_in[6];
  const float* env_b  = (const float*)d_in[7];
  const float* conv_w = (const float*)d_in[8];
  float* out = (float*)d_out;

  // workspace layout (floats): h | agg | e | dn | val  -> ~61 MB total
  float* ws  = (float*)d_ws;
  float* h   = ws;                 // NN*HH = 6.4e6
  float* agg = ws + 6400000;       // NN*HH
  float* e_g = ws + 12800000;      // NN*KK = 8e5
  float* dn  = ws + 13600000;      // NN
  float* val = ws + 13700000;      // EE = 1.6e6

  const int* row = ei;
  const int* col = ei + EE;

  // layer-invariant: degree norm per edge
  hipMemsetAsync(dn, 0, NN * sizeof(float), stream);
  deg_kernel<<<EE / 256, 256, 0, stream>>>(col, dn);
  dn_kernel<<<(NN + 255) / 256, 256, 0, stream>>>(dn);
  val_kernel<<<EE / 256, 256, 0, stream>>>(row, col, dn, val);

  fc0_kernel<<<(NN * HH) / 256, 256, 0, stream>>>(x, fc0_w, fc0_b, h);

  for (int l = 0; l < LL; ++l) {
    env_kernel<<<(NN + 255) / 256, 256, 0, stream>>>(
        h, env_w + l * (2 * HH * KK), env_b + l * KK, e_g);
    hipMemsetAsync(agg, 0, (size_t)NN * HH * sizeof(float), stream);
    scatter_kernel<<<(EE * 16) / 256, 256, 0, stream>>>(row, col, val, h, agg);
    conv_kernel<<<(NN * HH) / 256, 256, 0, stream>>>(
        h, agg, e_g, conv_w + l * (KK * 2 * HH * HH), 0);
  }

  fc1_kernel<<<(NN * CC) / 256, 256, 0, stream>>>(h, fc1_w, fc1_b, out);
}

// Round 3
// 1745.017 us; speedup vs baseline: 3.2255x; 3.2255x over previous
//
#include <hip/hip_runtime.h>
#include <math.h>

#define NN 100000
#define DD 128
#define HH 64
#define KK 8
#define LL 3
#define CC 16
#define EE 1600000
#define NB_SCAN 391  // ceil(NN/256)

// ---------------- CSR build (layer-invariant) ----------------

__global__ __launch_bounds__(256) void deg_kernel(const int* __restrict__ col,
                                                  int* __restrict__ deg) {
  int i = blockIdx.x * 256 + threadIdx.x;  // EE % 256 == 0
  atomicAdd(&deg[col[i]], 1);
}

__global__ __launch_bounds__(256) void dn_kernel(const int* __restrict__ deg,
                                                 float* __restrict__ dn) {
  int i = blockIdx.x * 256 + threadIdx.x;
  if (i < NN) {
    int d = deg[i];
    dn[i] = d > 0 ? 1.0f / sqrtf((float)d) : 0.0f;
  }
}

// 3-phase exclusive scan of deg -> offs
__global__ __launch_bounds__(256) void scan1_kernel(const int* __restrict__ deg,
                                                    int* __restrict__ offs,
                                                    int* __restrict__ bsum) {
  __shared__ int tmp[256];
  int t = threadIdx.x;
  int i = blockIdx.x * 256 + t;
  int v = (i < NN) ? deg[i] : 0;
  tmp[t] = v;
  __syncthreads();
#pragma unroll
  for (int d = 1; d < 256; d <<= 1) {
    int x = (t >= d) ? tmp[t - d] : 0;
    __syncthreads();
    tmp[t] += x;
    __syncthreads();
  }
  if (i < NN) offs[i] = tmp[t] - v;  // exclusive within block
  if (t == 255) bsum[blockIdx.x] = tmp[255];
}

__global__ __launch_bounds__(256) void scan2_kernel(int* __restrict__ bsum) {
  __shared__ int tmp[256];
  __shared__ int carry_s;
  int t = threadIdx.x;
  if (t == 0) carry_s = 0;
  __syncthreads();
  for (int base = 0; base < NB_SCAN; base += 256) {
    int i = base + t;
    int v = (i < NB_SCAN) ? bsum[i] : 0;
    tmp[t] = v;
    __syncthreads();
#pragma unroll
    for (int d = 1; d < 256; d <<= 1) {
      int x = (t >= d) ? tmp[t - d] : 0;
      __syncthreads();
      tmp[t] += x;
      __syncthreads();
    }
    int carry = carry_s;
    if (i < NB_SCAN) bsum[i] = carry + tmp[t] - v;  // exclusive
    __syncthreads();
    if (t == 0) carry_s = carry + tmp[255];
    __syncthreads();
  }
}

__global__ __launch_bounds__(256) void scan3_kernel(int* __restrict__ offs,
                                                    const int* __restrict__ bsum) {
  int i = blockIdx.x * 256 + threadIdx.x;
  if (i < NN) offs[i] += bsum[blockIdx.x];
}

// fill CSR: csr[pos] = (row, val) grouped by col
__global__ __launch_bounds__(256) void fill_kernel(const int* __restrict__ row,
                                                   const int* __restrict__ col,
                                                   const int* __restrict__ offs,
                                                   int* __restrict__ cursor,
                                                   const float* __restrict__ dn,
                                                   int2* __restrict__ csr) {
  int e = blockIdx.x * 256 + threadIdx.x;  // EE % 256 == 0
  int c = col[e], r = row[e];
  int pos = offs[c] + atomicAdd(&cursor[c], 1);
  int2 p;
  p.x = r;
  p.y = __float_as_int(dn[c] * dn[r]);
  csr[pos] = p;
}

// ---------------- fc0: h = relu(x @ fc0_w + b), [N,128]@[128,64] ----------------

__global__ __launch_bounds__(256) void fc0_kernel(const float* __restrict__ x,
                                                  const float* __restrict__ w,
                                                  const float* __restrict__ b,
                                                  float* __restrict__ h) {
  int id = blockIdx.x * 256 + threadIdx.x;  // (NN*HH) % 256 == 0
  int n = id >> 6, o = id & 63;
  const float* xr = x + n * DD;
  float s0 = 0.f, s1 = 0.f, s2 = 0.f, s3 = 0.f;
#pragma unroll
  for (int f = 0; f < DD; f += 4) {
    s0 = fmaf(xr[f + 0], w[(f + 0) * HH + o], s0);
    s1 = fmaf(xr[f + 1], w[(f + 1) * HH + o], s1);
    s2 = fmaf(xr[f + 2], w[(f + 2) * HH + o], s2);
    s3 = fmaf(xr[f + 3], w[(f + 3) * HH + o], s3);
  }
  h[id] = fmaxf((s0 + s1) + (s2 + s3) + b[o], 0.0f);
}

// ---------------- env gate: e = pi * (pi > theta), h_env == 0 always ----------------

__global__ __launch_bounds__(256) void env_kernel(const float* __restrict__ h,
                                                  const float* __restrict__ env_w,
                                                  const float* __restrict__ env_b,
                                                  float* __restrict__ e_out) {
  int n = blockIdx.x * 256 + threadIdx.x;
  if (n >= NN) return;
  float logit[KK];
#pragma unroll
  for (int k = 0; k < KK; ++k) logit[k] = env_b[k];
  const float4* hp = reinterpret_cast<const float4*>(h + n * HH);
#pragma unroll
  for (int f4 = 0; f4 < HH / 4; ++f4) {
    float4 hv = hp[f4];
    float hj[4] = {hv.x, hv.y, hv.z, hv.w};
#pragma unroll
    for (int j = 0; j < 4; ++j) {
      int f = f4 * 4 + j;
#pragma unroll
      for (int k = 0; k < KK; ++k)
        logit[k] = fmaf(hj[j], env_w[f * KK + k], logit[k]);
    }
  }
  float m = logit[0];
#pragma unroll
  for (int k = 1; k < KK; ++k) m = fmaxf(m, logit[k]);
  float p[KK];
  float s = 0.f;
#pragma unroll
  for (int k = 0; k < KK; ++k) {
    p[k] = expf(logit[k] - m);
    s += p[k];
  }
#pragma unroll
  for (int k = 0; k < KK; ++k) {
    float pi = p[k] / s;
    e_out[n * KK + k] = ((double)pi > 0.1) ? pi : 0.0f;
  }
}

// ---------------- GCN gather: agg[n,o] = sum_{edges into n} val * h[row,o] ----------------
// one wave per node, lane = output channel; no atomics.

__global__ __launch_bounds__(256) void gather_kernel(const int2* __restrict__ csr,
                                                     const int* __restrict__ offs,
                                                     const int* __restrict__ deg,
                                                     const float* __restrict__ h,
                                                     float* __restrict__ agg) {
  int n = blockIdx.x * 4 + (threadIdx.x >> 6);
  if (n >= NN) return;
  int lane = threadIdx.x & 63;
  int j = offs[n];
  int end = j + deg[n];
  float a0 = 0.f, a1 = 0.f, a2 = 0.f, a3 = 0.f;
  for (; j + 3 < end; j += 4) {
    int2 p0 = csr[j], p1 = csr[j + 1], p2 = csr[j + 2], p3 = csr[j + 3];
    float h0 = h[p0.x * HH + lane];
    float h1 = h[p1.x * HH + lane];
    float h2 = h[p2.x * HH + lane];
    float h3 = h[p3.x * HH + lane];
    a0 = fmaf(h0, __int_as_float(p0.y), a0);
    a1 = fmaf(h1, __int_as_float(p1.y), a1);
    a2 = fmaf(h2, __int_as_float(p2.y), a2);
    a3 = fmaf(h3, __int_as_float(p3.y), a3);
  }
  for (; j < end; ++j) {
    int2 p = csr[j];
    a0 = fmaf(h[p.x * HH + lane], __int_as_float(p.y), a0);
  }
  agg[n * HH + lane] = (a0 + a1) + (a2 + a3);
}

// ---------------- gated K-head conv + residual relu (in-place on h) ----------------

__global__ __launch_bounds__(256) void conv_kernel(float* __restrict__ h,
                                                   const float* __restrict__ agg,
                                                   const float* __restrict__ eg,
                                                   const float* __restrict__ w) {
  int id = blockIdx.x * 256 + threadIdx.x;  // (NN*HH) % 256 == 0
  int n = id >> 6, o = id & 63;
  int ln = threadIdx.x >> 6;
  __shared__ float hi_s[4][2 * HH];
  hi_s[ln][o] = agg[n * HH + o];
  hi_s[ln][HH + o] = h[n * HH + o];
  __syncthreads();
  float acc = 0.f;
  for (int k = 0; k < KK; ++k) {
    float ek = eg[n * KK + k];
    if (ek != 0.0f) {  // wave-uniform branch
      const float* wk = w + k * (2 * HH * HH) + o;
      float s0 = 0.f, s1 = 0.f, s2 = 0.f, s3 = 0.f;
#pragma unroll
      for (int f = 0; f < 2 * HH; f += 4) {
        s0 = fmaf(hi_s[ln][f + 0], wk[(f + 0) * HH], s0);
        s1 = fmaf(hi_s[ln][f + 1], wk[(f + 1) * HH], s1);
        s2 = fmaf(hi_s[ln][f + 2], wk[(f + 2) * HH], s2);
        s3 = fmaf(hi_s[ln][f + 3], wk[(f + 3) * HH], s3);
      }
      acc = fmaf(ek, (s0 + s1) + (s2 + s3), acc);
    }
  }
  h[n * HH + o] = fmaxf(hi_s[ln][HH + o] + acc, 0.0f);
}

// ---------------- fc1: out = h @ fc1_w + b, [N,64]@[64,16] ----------------

__global__ __launch_bounds__(256) void fc1_kernel(const float* __restrict__ h,
                                                  const float* __restrict__ w,
                                                  const float* __restrict__ b,
                                                  float* __restrict__ out) {
  int id = blockIdx.x * 256 + threadIdx.x;  // (NN*CC) % 256 == 0
  int n = id >> 4, c = id & 15;
  const float* hr = h + n * HH;
  float acc = b[c];
#pragma unroll
  for (int o = 0; o < HH; ++o) acc = fmaf(hr[o], w[o * CC + c], acc);
  out[id] = acc;
}

// ---------------- launch ----------------

extern "C" void kernel_launch(void* const* d_in, const int* in_sizes, int n_in,
                              void* d_out, int out_size, void* d_ws, size_t ws_size,
                              hipStream_t stream) {
  const float* x      = (const float*)d_in[0];
  const int*   ei     = (const int*)d_in[1];
  const float* fc0_w  = (const float*)d_in[2];
  const float* fc0_b  = (const float*)d_in[3];
  const float* fc1_w  = (const float*)d_in[4];
  const float* fc1_b  = (const float*)d_in[5];
  const float* env_w  = (const float*)d_in[6];
  const float* env_b  = (const float*)d_in[7];
  const float* conv_w = (const float*)d_in[8];
  float* out = (float*)d_out;

  // workspace layout (4B units), total ~68.8 MB
  float* ws   = (float*)d_ws;
  float* h    = ws;                        // 6,400,000
  float* agg  = ws + 6400000;              // 6,400,000
  float* e_g  = ws + 12800000;             // 800,000
  float* dn   = ws + 13600000;             // 100,000
  int*   degi = (int*)(ws + 13700000);     // 100,000
  int*   offs = (int*)(ws + 13800000);     // 100,000
  int*   curs = (int*)(ws + 13900000);     // 100,000
  int*   bsum = (int*)(ws + 14000000);     // 1,024
  int2*  csr  = (int2*)(ws + 14002000);    // 1,600,000 * 8B (8B-aligned offset)

  const int* row = ei;
  const int* col = ei + EE;

  // CSR build (once; layer-invariant)
  hipMemsetAsync(degi, 0, NN * sizeof(int), stream);
  hipMemsetAsync(curs, 0, NN * sizeof(int), stream);
  deg_kernel<<<EE / 256, 256, 0, stream>>>(col, degi);
  dn_kernel<<<NB_SCAN, 256, 0, stream>>>(degi, dn);
  scan1_kernel<<<NB_SCAN, 256, 0, stream>>>(degi, offs, bsum);
  scan2_kernel<<<1, 256, 0, stream>>>(bsum);
  scan3_kernel<<<NB_SCAN, 256, 0, stream>>>(offs, bsum);
  fill_kernel<<<EE / 256, 256, 0, stream>>>(row, col, offs, curs, dn, csr);

  fc0_kernel<<<(NN * HH) / 256, 256, 0, stream>>>(x, fc0_w, fc0_b, h);

  for (int l = 0; l < LL; ++l) {
    env_kernel<<<NB_SCAN, 256, 0, stream>>>(
        h, env_w + l * (2 * HH * KK), env_b + l * KK, e_g);
    gather_kernel<<<(NN + 3) / 4, 256, 0, stream>>>(csr, offs, degi, h, agg);
    conv_kernel<<<(NN * HH) / 256, 256, 0, stream>>>(
        h, agg, e_g, conv_w + l * (KK * 2 * HH * HH));
  }

  fc1_kernel<<<(NN * CC) / 256, 256, 0, stream>>>(h, fc1_w, fc1_b, out);
}